// Round 3
// baseline (507.904 us; speedup 1.0000x reference)
//
#include <hip/hip_runtime.h>

#define TSEQ 512
#define BSZN 4
#define NH 16
#define NBN 32
#define EMB 1024
#define HD 64
#define TGT 1536
#define MROWS 6144

typedef unsigned short ushort_t;
typedef __bf16 bf8 __attribute__((ext_vector_type(8)));
typedef unsigned short u16x4 __attribute__((ext_vector_type(4)));
typedef float f32x4 __attribute__((ext_vector_type(4)));

__device__ __forceinline__ unsigned short f2bf(float f) {
  unsigned int u = __builtin_bit_cast(unsigned int, f);
  u += 0x7fffu + ((u >> 16) & 1u);
  return (unsigned short)(u >> 16);
}

__device__ __forceinline__ float bf2f(unsigned short u) {
  return __builtin_bit_cast(float, (unsigned int)u << 16);
}

__device__ __forceinline__ void gload16(const void* g, void* l) {
  __builtin_amdgcn_global_load_lds(
      (const __attribute__((address_space(1))) void*)g,
      (__attribute__((address_space(3))) void*)l, 16, 0, 0);
}

__device__ __forceinline__ f32x4 mfma_bf16(bf8 a, bf8 b, f32x4 c) {
  return __builtin_amdgcn_mfma_f32_16x16x32_bf16(a, b, c, 0, 0, 0);
}

// ---------------- fp32 -> bf16 convert (fused: 4 segments) ----------------
__global__ void cvt4_kernel(const float* __restrict__ q, const float* __restrict__ win,
                            const float* __restrict__ wout, const float* __restrict__ wrel,
                            ushort_t* __restrict__ qo, ushort_t* __restrict__ wino,
                            ushort_t* __restrict__ wouto, ushort_t* __restrict__ wrelo) {
  const int i = blockIdx.x * blockDim.x + threadIdx.x;
  const int nq = 1572864, nwin = 786432, nwout = 262144, nwrel = 131072;
  const float* src;
  ushort_t* dst;
  int off;
  if (i < nq) { src = q; dst = qo; off = i; }
  else if (i < nq + nwin) { src = win; dst = wino; off = i - nq; }
  else if (i < nq + nwin + nwout) { src = wout; dst = wouto; off = i - nq - nwin; }
  else if (i < nq + nwin + nwout + nwrel) { src = wrel; dst = wrelo; off = i - nq - nwin - nwout; }
  else return;
  const float4 v = reinterpret_cast<const float4*>(src)[off];
  ushort4 o;
  o.x = f2bf(v.x); o.y = f2bf(v.y); o.z = f2bf(v.z); o.w = f2bf(v.w);
  reinterpret_cast<ushort4*>(dst)[off] = o;
}

// ---------------- GEMM: C[M,N] = A[M,K] * B[N,K]^T + bias ----------------
// MODE 0: qkv proj -> Q(scaled)/K/[bh][t][hd], Vt [bh][hd][t] (bf16)
// MODE 2: fp32 C
// MODE 3: bf16 C (into Qo)
template <int MODE>
__global__ __launch_bounds__(256) void gemm_bt(
    const ushort_t* __restrict__ A, const ushort_t* __restrict__ B,
    const float* __restrict__ bias, float* __restrict__ Cf,
    ushort_t* __restrict__ Qo, ushort_t* __restrict__ Ko, ushort_t* __restrict__ Vto,
    int M, int N, int K) {
  __shared__ ushort_t lA[128 * 32];
  __shared__ ushort_t lB[128 * 32];
  const int tid = threadIdx.x;
  const int lane = tid & 63;
  const int wid = tid >> 6;
  const int l15 = lane & 15, l4 = lane >> 4;
  const int bm = blockIdx.y, bn = blockIdx.x;
  const int wm = (wid >> 1) * 64, wn = (wid & 1) * 64;

  f32x4 acc[4][4] = {};

  const int srow = tid >> 2;
  const int scol = (tid & 3) * 8;
  const ushort_t* Ag = A + (size_t)(bm * 128 + srow) * K + scol;
  const ushort_t* Bg = B + (size_t)(bn * 128 + srow) * K + scol;
  ushort_t* lAp = &lA[srow * 32 + scol];
  ushort_t* lBp = &lB[srow * 32 + scol];

  for (int kt = 0; kt < K; kt += 32) {
    __syncthreads();
    gload16(Ag + kt, lAp);
    gload16(Ag + kt + (size_t)64 * K, lAp + 64 * 32);
    gload16(Bg + kt, lBp);
    gload16(Bg + kt + (size_t)64 * K, lBp + 64 * 32);
    __syncthreads();
    bf8 af[4], bv[4];
#pragma unroll
    for (int mi = 0; mi < 4; ++mi)
      af[mi] = *reinterpret_cast<const bf8*>(&lA[(wm + mi * 16 + l15) * 32 + l4 * 8]);
#pragma unroll
    for (int ni = 0; ni < 4; ++ni)
      bv[ni] = *reinterpret_cast<const bf8*>(&lB[(wn + ni * 16 + l15) * 32 + l4 * 8]);
#pragma unroll
    for (int mi = 0; mi < 4; ++mi)
#pragma unroll
      for (int ni = 0; ni < 4; ++ni)
        acc[mi][ni] = mfma_bf16(af[mi], bv[ni], acc[mi][ni]);
  }

#pragma unroll
  for (int ni = 0; ni < 4; ++ni) {
    const int col = bn * 128 + wn + ni * 16 + l15;
    const float bc = bias[col];
#pragma unroll
    for (int mi = 0; mi < 4; ++mi) {
      const int row0 = bm * 128 + wm + mi * 16 + l4 * 4;
      f32x4 v = acc[mi][ni];
#pragma unroll
      for (int r = 0; r < 4; ++r) {
        const int row = row0 + r;
        float val = v[r] + bc;
        if (MODE == 0) {
          const int part = col >> 10;
          const int cc = col & 1023;
          const int h = cc >> 6, d = cc & 63;
          const int t = row >> 2, bb = row & 3;
          const int bh = bb * NH + h;
          if (part == 0) {
            Qo[((size_t)bh * TGT + t) * HD + d] = f2bf(val * 0.125f);
          } else if (part == 1) {
            Ko[((size_t)bh * TGT + t) * HD + d] = f2bf(val);
          } else {
            Vto[((size_t)bh * HD + d) * TGT + t] = f2bf(val);
          }
        } else if (MODE == 3) {
          Qo[(size_t)row * N + col] = f2bf(val);
        } else {
          Cf[(size_t)row * N + col] = val;
        }
      }
    }
  }
}

// ---------------- fused attention (main + ngram), flash-style ----------------
// grid: (tile 0..31, bh 0..63, z 0..2)  -- tile fastest for K/V L2 reuse;
// the 16 h-blocks sharing (b,tile) sit at stride 32 = same XCD -> ib/mask L2 reuse.
__global__ __launch_bounds__(256, 4) void attn_kernel(
    const ushort_t* __restrict__ Q, const ushort_t* __restrict__ Kb,
    const ushort_t* __restrict__ Vt, const ushort_t* __restrict__ VMb,
    const int* __restrict__ ib_main, const int* __restrict__ ib_rel,
    const float* __restrict__ mask_main, const float* __restrict__ mask_ng,
    ushort_t* __restrict__ AT) {
  __shared__ float S[16][516];          // P (bf16) overwrites each row in place
  __shared__ float red_m[16], red_s[16], red_r[16];
  ushort_t* Pb = reinterpret_cast<ushort_t*>(&S[0][0]);  // row stride 1032 ushorts

  const int tile = blockIdx.x;
  const int bh = blockIdx.y;
  const int z = blockIdx.z;
  const int b = bh >> 4, h = bh & 15;
  const int t0 = tile * 16;
  const int tid = threadIdx.x;
  const int lane = tid & 63, wid = tid >> 6;
  const int l15 = lane & 15, l4 = lane >> 4;

  const int g = z - 1;
  const int nchunk = (z == 0) ? 1 : 2;
  const int qrow0 = (z == 0) ? t0 : TSEQ + g * TSEQ + t0;

  if (tid < 16) { red_m[tid] = -1e30f; red_s[tid] = 0.f; }

  const ushort_t* qp = &Q[((size_t)bh * TGT + qrow0 + l15) * HD + l4 * 8];
  bf8 qf0 = *reinterpret_cast<const bf8*>(qp);
  bf8 qf1 = *reinterpret_cast<const bf8*>(qp + 32);

  f32x4 oacc = {};
  const int d0 = wid * 16;

  for (int ch = 0; ch < nchunk; ++ch) {
    const int srow0 = (ch == 0) ? 0 : TSEQ + g * TSEQ;

    // ---- issue bucket-index loads first (HBM latency hides under QK)
    int4 iba[4], ibb[4];
#pragma unroll
    for (int rr = 0; rr < 4; ++rr) {
      const int tloc = t0 + wid * 4 + rr;
      const int* ibrow = (z == 0)
          ? ib_main + ((size_t)b * TSEQ + tloc) * TSEQ
          : ib_rel + ((size_t)b * TSEQ + tloc) * (2 * TSEQ) + ch * TSEQ;
      iba[rr] = *reinterpret_cast<const int4*>(ibrow + lane * 4);
      ibb[rr] = *reinterpret_cast<const int4*>(ibrow + 256 + lane * 4);
    }

    // ---- QK^T: this wave covers cols [wid*128, wid*128+128)
#pragma unroll
    for (int ni = 0; ni < 8; ++ni) {
      const int s0 = wid * 128 + ni * 16;
      const ushort_t* kp = &Kb[((size_t)bh * TGT + srow0 + s0 + l15) * HD + l4 * 8];
      bf8 kf0 = *reinterpret_cast<const bf8*>(kp);
      bf8 kf1 = *reinterpret_cast<const bf8*>(kp + 32);
      f32x4 s4 = {};
      __builtin_amdgcn_s_setprio(1);
      s4 = mfma_bf16(qf0, kf0, s4);
      s4 = mfma_bf16(qf1, kf1, s4);
      __builtin_amdgcn_s_setprio(0);
#pragma unroll
      for (int r = 0; r < 4; ++r) S[l4 * 4 + r][s0 + l15] = s4[r];
    }

    // ---- gather rel-values + mask -> addv regs (L2 hits; overlaps QK tail &
    //      other waves' MFMA; completes before we need them post-barrier)
    float addv[4][8];
#pragma unroll
    for (int rr = 0; rr < 4; ++rr) {
      const int tloc = t0 + wid * 4 + rr;
      const int qglob = qrow0 + wid * 4 + rr;
      const float* mrow = (z == 0)
          ? mask_main + (size_t)tloc * TSEQ
          : mask_ng + ((size_t)g * TSEQ + tloc) * (2 * TSEQ) + ch * TSEQ;
      const ushort_t* vmp = VMb + (size_t)(qglob * BSZN + b) * (NBN * NH);
      const float4 mk0 = *reinterpret_cast<const float4*>(mrow + lane * 4);
      const float4 mk1 = *reinterpret_cast<const float4*>(mrow + 256 + lane * 4);
      addv[rr][0] = bf2f(vmp[iba[rr].x * NH + h]) + mk0.x;
      addv[rr][1] = bf2f(vmp[iba[rr].y * NH + h]) + mk0.y;
      addv[rr][2] = bf2f(vmp[iba[rr].z * NH + h]) + mk0.z;
      addv[rr][3] = bf2f(vmp[iba[rr].w * NH + h]) + mk0.w;
      addv[rr][4] = bf2f(vmp[ibb[rr].x * NH + h]) + mk1.x;
      addv[rr][5] = bf2f(vmp[ibb[rr].y * NH + h]) + mk1.y;
      addv[rr][6] = bf2f(vmp[ibb[rr].z * NH + h]) + mk1.z;
      addv[rr][7] = bf2f(vmp[ibb[rr].w * NH + h]) + mk1.w;
    }
    __syncthreads();

    // ---- softmax: wave owns rows wid*4..wid*4+3; pure LDS + VALU now
    u16x4 plo[4], phi[4];
#pragma unroll
    for (int rr = 0; rr < 4; ++rr) {
      const int r = wid * 4 + rr;
      const float4 s0 = *reinterpret_cast<const float4*>(&S[r][lane * 4]);
      const float4 s1 = *reinterpret_cast<const float4*>(&S[r][256 + lane * 4]);
      float vals[8];
      vals[0] = s0.x + addv[rr][0];
      vals[1] = s0.y + addv[rr][1];
      vals[2] = s0.z + addv[rr][2];
      vals[3] = s0.w + addv[rr][3];
      vals[4] = s1.x + addv[rr][4];
      vals[5] = s1.y + addv[rr][5];
      vals[6] = s1.z + addv[rr][6];
      vals[7] = s1.w + addv[rr][7];
      float mx = fmaxf(fmaxf(fmaxf(vals[0], vals[1]), fmaxf(vals[2], vals[3])),
                       fmaxf(fmaxf(vals[4], vals[5]), fmaxf(vals[6], vals[7])));
#pragma unroll
      for (int off = 32; off > 0; off >>= 1) mx = fmaxf(mx, __shfl_xor(mx, off));
      const float oldm = red_m[r];
      const float newm = fmaxf(oldm, mx);
      float sum = 0.f;
#pragma unroll
      for (int j = 0; j < 4; ++j) {
        const float p = __expf(vals[j] - newm);
        sum += p;
        plo[rr][j] = f2bf(p);
      }
#pragma unroll
      for (int j = 0; j < 4; ++j) {
        const float p = __expf(vals[4 + j] - newm);
        sum += p;
        phi[rr][j] = f2bf(p);
      }
#pragma unroll
      for (int off = 32; off > 0; off >>= 1) sum += __shfl_xor(sum, off);
      if (lane == 0) {
        const float rsc = (oldm <= -1e30f) ? 0.f : __expf(oldm - newm);
        red_r[r] = rsc;
        red_s[r] = red_s[r] * rsc + sum;
        red_m[r] = newm;
      }
    }
    // all S reads for this wave's rows are done; overwrite rows with bf16 P
    asm volatile("" ::: "memory");
    __builtin_amdgcn_sched_barrier(0);
#pragma unroll
    for (int rr = 0; rr < 4; ++rr) {
      const int r = wid * 4 + rr;
      *reinterpret_cast<u16x4*>(Pb + (size_t)r * 1032 + lane * 4) = plo[rr];
      *reinterpret_cast<u16x4*>(Pb + (size_t)r * 1032 + 256 + lane * 4) = phi[rr];
    }
    __syncthreads();

    // ---- rescale + PV: this wave owns d-tile d0 = wid*16
    {
      f32x4 rs;
#pragma unroll
      for (int r = 0; r < 4; ++r) rs[r] = red_r[l4 * 4 + r];
      oacc *= rs;
    }
#pragma unroll
    for (int ks = 0; ks < 16; ++ks) {
      bf8 pa = *reinterpret_cast<const bf8*>(&Pb[(size_t)l15 * 1032 + ks * 32 + l4 * 8]);
      bf8 vb = *reinterpret_cast<const bf8*>(
          &Vt[((size_t)bh * HD + d0 + l15) * TGT + srow0 + ks * 32 + l4 * 8]);
      __builtin_amdgcn_s_setprio(1);
      oacc = mfma_bf16(pa, vb, oacc);
      __builtin_amdgcn_s_setprio(0);
    }
    __syncthreads();
  }

#pragma unroll
  for (int r = 0; r < 4; ++r) {
    const int row = l4 * 4 + r;
    const float inv = 1.f / red_s[row];
    const int tout = qrow0 + row;
    AT[((size_t)tout * BSZN + b) * EMB + h * HD + d0 + l15] = f2bf(oacc[r] * inv);
  }
}

extern "C" void kernel_launch(void* const* d_in, const int* in_sizes, int n_in,
                              void* d_out, int out_size, void* d_ws, size_t ws_size,
                              hipStream_t stream) {
  const float* query     = (const float*)d_in[0];
  const float* mask_main = (const float*)d_in[1];
  const float* mask_ng   = (const float*)d_in[2];
  const int*   ib_main   = (const int*)d_in[3];
  const int*   ib_rel    = (const int*)d_in[4];
  const float* w_in      = (const float*)d_in[5];
  const float* b_in      = (const float*)d_in[6];
  const float* w_out     = (const float*)d_in[7];
  const float* b_out     = (const float*)d_in[8];
  const float* w_rel     = (const float*)d_in[9];
  const float* b_rel     = (const float*)d_in[10];
  float* out = (float*)d_out;

  ushort_t* qbf    = (ushort_t*)d_ws;           // 6144*1024
  ushort_t* winbf  = qbf + 6291456;             // 3072*1024
  ushort_t* woutbf = winbf + 3145728;           // 1024*1024
  ushort_t* relwbf = woutbf + 1048576;          // 512*1024
  ushort_t* Qb     = relwbf + 524288;           // 64*1536*64
  ushort_t* Kbuf   = Qb + 6291456;
  ushort_t* Vtb    = Kbuf + 6291456;
  ushort_t* VMb    = Vtb + 6291456;             // 6144*512 bf16
  ushort_t* AT     = VMb + 3145728;             // 6144*1024

  // fp32 -> bf16 (single fused launch)
  {
    const int total4 = 1572864 + 786432 + 262144 + 131072;
    cvt4_kernel<<<(total4 + 255) / 256, 256, 0, stream>>>(query, w_in, w_out, w_rel,
                                                          qbf, winbf, woutbf, relwbf);
  }

  // in-projection -> Q/K/Vt
  gemm_bt<0><<<dim3(24, 48), 256, 0, stream>>>(qbf, winbf, b_in, nullptr,
                                               Qb, Kbuf, Vtb, MROWS, 3072, 1024);
  // relative-value table VM (bf16)
  gemm_bt<3><<<dim3(4, 48), 256, 0, stream>>>(qbf, relwbf, b_rel, nullptr,
                                              VMb, nullptr, nullptr, MROWS, 512, 1024);
  // fused attention (main + 2 ngram streams)
  attn_kernel<<<dim3(32, 64, 3), 256, 0, stream>>>(Qb, Kbuf, Vtb, VMb, ib_main, ib_rel,
                                                   mask_main, mask_ng, AT);
  // out-projection
  gemm_bt<2><<<dim3(8, 48), 256, 0, stream>>>(AT, woutbf, b_out, out,
                                              nullptr, nullptr, nullptr, MROWS, 1024, 1024);
}

// Round 4
// 403.456 us; speedup vs baseline: 1.2589x; 1.2589x over previous
//
#include <hip/hip_runtime.h>

#define TSEQ 512
#define BSZN 4
#define NH 16
#define NBN 32
#define EMB 1024
#define HD 64
#define TGT 1536
#define MROWS 6144

typedef unsigned short ushort_t;
typedef __bf16 bf8 __attribute__((ext_vector_type(8)));
typedef unsigned short u16x4 __attribute__((ext_vector_type(4)));
typedef float f32x4 __attribute__((ext_vector_type(4)));

__device__ __forceinline__ unsigned short f2bf(float f) {
  unsigned int u = __builtin_bit_cast(unsigned int, f);
  u += 0x7fffu + ((u >> 16) & 1u);
  return (unsigned short)(u >> 16);
}

__device__ __forceinline__ float bf2f(unsigned short u) {
  return __builtin_bit_cast(float, (unsigned int)u << 16);
}

__device__ __forceinline__ void gload16(const void* g, void* l) {
  __builtin_amdgcn_global_load_lds(
      (const __attribute__((address_space(1))) void*)g,
      (__attribute__((address_space(3))) void*)l, 16, 0, 0);
}

__device__ __forceinline__ f32x4 mfma_bf16(bf8 a, bf8 b, f32x4 c) {
  return __builtin_amdgcn_mfma_f32_16x16x32_bf16(a, b, c, 0, 0, 0);
}

// ---------------- fp32 -> bf16 convert (6 segments incl. masks) ----------------
__global__ void cvt6_kernel(const float* __restrict__ q, const float* __restrict__ win,
                            const float* __restrict__ wout, const float* __restrict__ wrel,
                            const float* __restrict__ mm, const float* __restrict__ mng,
                            ushort_t* __restrict__ qo, ushort_t* __restrict__ wino,
                            ushort_t* __restrict__ wouto, ushort_t* __restrict__ wrelo,
                            ushort_t* __restrict__ mmo, ushort_t* __restrict__ mngo) {
  const int i = blockIdx.x * blockDim.x + threadIdx.x;
  const int n0 = 1572864, n1 = 786432, n2 = 262144, n3 = 131072, n4 = 65536, n5 = 262144;
  const float* src;
  ushort_t* dst;
  int off;
  if (i < n0) { src = q; dst = qo; off = i; }
  else if (i < n0 + n1) { src = win; dst = wino; off = i - n0; }
  else if (i < n0 + n1 + n2) { src = wout; dst = wouto; off = i - n0 - n1; }
  else if (i < n0 + n1 + n2 + n3) { src = wrel; dst = wrelo; off = i - n0 - n1 - n2; }
  else if (i < n0 + n1 + n2 + n3 + n4) { src = mm; dst = mmo; off = i - n0 - n1 - n2 - n3; }
  else if (i < n0 + n1 + n2 + n3 + n4 + n5) { src = mng; dst = mngo; off = i - n0 - n1 - n2 - n3 - n4; }
  else return;
  const float4 v = reinterpret_cast<const float4*>(src)[off];
  ushort4 o;
  o.x = f2bf(v.x); o.y = f2bf(v.y); o.z = f2bf(v.z); o.w = f2bf(v.w);
  reinterpret_cast<ushort4*>(dst)[off] = o;
}

// ---------------- bucket indices int32 -> u8 (values < 32) ----------------
__global__ void prep_ib_kernel(const int* __restrict__ ibm, const int* __restrict__ ibr,
                               unsigned char* __restrict__ obm, unsigned char* __restrict__ obr) {
  const int i = blockIdx.x * blockDim.x + threadIdx.x;
  const int nm4 = 262144, nr4 = 524288;
  if (i < nm4) {
    const int4 v = reinterpret_cast<const int4*>(ibm)[i];
    uchar4 o;
    o.x = (unsigned char)v.x; o.y = (unsigned char)v.y;
    o.z = (unsigned char)v.z; o.w = (unsigned char)v.w;
    reinterpret_cast<uchar4*>(obm)[i] = o;
  } else if (i < nm4 + nr4) {
    const int j = i - nm4;
    const int4 v = reinterpret_cast<const int4*>(ibr)[j];
    uchar4 o;
    o.x = (unsigned char)v.x; o.y = (unsigned char)v.y;
    o.z = (unsigned char)v.z; o.w = (unsigned char)v.w;
    reinterpret_cast<uchar4*>(obr)[j] = o;
  }
}

// ---------------- GEMM: C[M,N] = A[M,K] * B[N,K]^T + bias ----------------
// MODE 0: qkv proj -> Q(scaled)/K [bh][t][hd], Vt [bh][hd][t] (bf16)
// MODE 2: fp32 C
// MODE 3: bf16 C (into Qo)
template <int MODE>
__global__ __launch_bounds__(256) void gemm_bt(
    const ushort_t* __restrict__ A, const ushort_t* __restrict__ B,
    const float* __restrict__ bias, float* __restrict__ Cf,
    ushort_t* __restrict__ Qo, ushort_t* __restrict__ Ko, ushort_t* __restrict__ Vto,
    int M, int N, int K) {
  __shared__ ushort_t lA[128 * 32];
  __shared__ ushort_t lB[128 * 32];
  const int tid = threadIdx.x;
  const int lane = tid & 63;
  const int wid = tid >> 6;
  const int l15 = lane & 15, l4 = lane >> 4;
  const int bm = blockIdx.y, bn = blockIdx.x;
  const int wm = (wid >> 1) * 64, wn = (wid & 1) * 64;

  f32x4 acc[4][4] = {};

  const int srow = tid >> 2;
  const int scol = (tid & 3) * 8;
  const ushort_t* Ag = A + (size_t)(bm * 128 + srow) * K + scol;
  const ushort_t* Bg = B + (size_t)(bn * 128 + srow) * K + scol;
  ushort_t* lAp = &lA[srow * 32 + scol];
  ushort_t* lBp = &lB[srow * 32 + scol];

  for (int kt = 0; kt < K; kt += 32) {
    __syncthreads();
    gload16(Ag + kt, lAp);
    gload16(Ag + kt + (size_t)64 * K, lAp + 64 * 32);
    gload16(Bg + kt, lBp);
    gload16(Bg + kt + (size_t)64 * K, lBp + 64 * 32);
    __syncthreads();
    bf8 af[4], bv[4];
#pragma unroll
    for (int mi = 0; mi < 4; ++mi)
      af[mi] = *reinterpret_cast<const bf8*>(&lA[(wm + mi * 16 + l15) * 32 + l4 * 8]);
#pragma unroll
    for (int ni = 0; ni < 4; ++ni)
      bv[ni] = *reinterpret_cast<const bf8*>(&lB[(wn + ni * 16 + l15) * 32 + l4 * 8]);
#pragma unroll
    for (int mi = 0; mi < 4; ++mi)
#pragma unroll
      for (int ni = 0; ni < 4; ++ni)
        acc[mi][ni] = mfma_bf16(af[mi], bv[ni], acc[mi][ni]);
  }

#pragma unroll
  for (int ni = 0; ni < 4; ++ni) {
    const int col = bn * 128 + wn + ni * 16 + l15;
    const float bc = bias[col];
#pragma unroll
    for (int mi = 0; mi < 4; ++mi) {
      const int row0 = bm * 128 + wm + mi * 16 + l4 * 4;
      f32x4 v = acc[mi][ni];
#pragma unroll
      for (int r = 0; r < 4; ++r) {
        const int row = row0 + r;
        float val = v[r] + bc;
        if (MODE == 0) {
          const int part = col >> 10;
          const int cc = col & 1023;
          const int h = cc >> 6, d = cc & 63;
          const int t = row >> 2, bb = row & 3;
          const int bh = bb * NH + h;
          if (part == 0) {
            Qo[((size_t)bh * TGT + t) * HD + d] = f2bf(val * 0.125f);
          } else if (part == 1) {
            Ko[((size_t)bh * TGT + t) * HD + d] = f2bf(val);
          } else {
            Vto[((size_t)bh * HD + d) * TGT + t] = f2bf(val);
          }
        } else if (MODE == 3) {
          Qo[(size_t)row * N + col] = f2bf(val);
        } else {
          Cf[(size_t)row * N + col] = val;
        }
      }
    }
  }
}

// ---------------- fused attention, 8 heads per block ----------------
template <int NCHUNK>
__device__ __forceinline__ void attn_body(
    const int b, const int tile, const int g, const int hg,
    const ushort_t* __restrict__ Q, const ushort_t* __restrict__ Kb,
    const ushort_t* __restrict__ Vt, const ushort_t* __restrict__ VMb,
    const unsigned char* __restrict__ ib8b, const int ib_stride,
    const ushort_t* __restrict__ maskb, const int mask_stride,
    const int qrow0, ushort_t* __restrict__ AT,
    float (*S)[516], ushort_t* VM_lds,
    float* red_m, float* red_s, float* red_r) {
  const int tid = threadIdx.x;
  const int lane = tid & 63, wid = tid >> 6;
  const int l15 = lane & 15, l4 = lane >> 4;
  const int t0 = tile * 16;
  const int d0 = wid * 16;
  ushort_t* Pb = reinterpret_cast<ushort_t*>(&S[0][0]);  // row stride 1032 u16

  // ---- stage VM rows (16 x 512 u16) once per block; wave-uniform LDS dest
#pragma unroll
  for (int it = 0; it < 4; ++it) {
    const int r = it * 4 + wid;
    gload16(VMb + ((size_t)(qrow0 + r) * BSZN + b) * (NBN * NH) + lane * 8,
            VM_lds + r * 512);
  }

  // ---- per-thread mask (bf16) + bucket (u8) registers, once per block
  u16x4 mpk[NCHUNK][4][2];
  uchar4 ibo[NCHUNK][4][2];
#pragma unroll
  for (int ch = 0; ch < NCHUNK; ++ch) {
#pragma unroll
    for (int rr = 0; rr < 4; ++rr) {
      const int tloc = t0 + wid * 4 + rr;
      const ushort_t* mrow = maskb + (size_t)tloc * mask_stride + ch * 512;
      mpk[ch][rr][0] = *reinterpret_cast<const u16x4*>(mrow + lane * 4);
      mpk[ch][rr][1] = *reinterpret_cast<const u16x4*>(mrow + 256 + lane * 4);
      const unsigned char* ibrow = ib8b + (size_t)tloc * ib_stride + ch * 512;
      ibo[ch][rr][0] = *reinterpret_cast<const uchar4*>(ibrow + lane * 4);
      ibo[ch][rr][1] = *reinterpret_cast<const uchar4*>(ibrow + 256 + lane * 4);
    }
  }

  for (int hh = 0; hh < 8; ++hh) {
    const int h = hg * 8 + hh;
    const int bh = b * NH + h;
    if (tid < 16) { red_m[tid] = -1e30f; red_s[tid] = 0.f; }

    const ushort_t* qp = &Q[((size_t)bh * TGT + qrow0 + l15) * HD + l4 * 8];
    const bf8 qf0 = *reinterpret_cast<const bf8*>(qp);
    const bf8 qf1 = *reinterpret_cast<const bf8*>(qp + 32);
    f32x4 oacc = {};

#pragma unroll
    for (int ch = 0; ch < NCHUNK; ++ch) {
      const int srow0 = (ch == 0) ? 0 : TSEQ + g * TSEQ;

      // ---- QK^T: wave covers cols [wid*128, wid*128+128)
#pragma unroll
      for (int ni = 0; ni < 8; ++ni) {
        const int s0 = wid * 128 + ni * 16;
        const ushort_t* kp = &Kb[((size_t)bh * TGT + srow0 + s0 + l15) * HD + l4 * 8];
        const bf8 kf0 = *reinterpret_cast<const bf8*>(kp);
        const bf8 kf1 = *reinterpret_cast<const bf8*>(kp + 32);
        f32x4 s4 = {};
        __builtin_amdgcn_s_setprio(1);
        s4 = mfma_bf16(qf0, kf0, s4);
        s4 = mfma_bf16(qf1, kf1, s4);
        __builtin_amdgcn_s_setprio(0);
#pragma unroll
        for (int r = 0; r < 4; ++r) S[l4 * 4 + r][s0 + l15] = s4[r];
      }
      __syncthreads();

      // ---- softmax: wave owns rows wid*4..+3; gathers hit LDS VM table
      u16x4 plo[4], phi[4];
#pragma unroll
      for (int rr = 0; rr < 4; ++rr) {
        const int r = wid * 4 + rr;
        const float4 s0v = *reinterpret_cast<const float4*>(&S[r][lane * 4]);
        const float4 s1v = *reinterpret_cast<const float4*>(&S[r][256 + lane * 4]);
        const ushort_t* vrow = VM_lds + r * 512;
        float vals[8];
        vals[0] = s0v.x + bf2f(mpk[ch][rr][0][0]) + bf2f(vrow[(int)ibo[ch][rr][0].x * NH + h]);
        vals[1] = s0v.y + bf2f(mpk[ch][rr][0][1]) + bf2f(vrow[(int)ibo[ch][rr][0].y * NH + h]);
        vals[2] = s0v.z + bf2f(mpk[ch][rr][0][2]) + bf2f(vrow[(int)ibo[ch][rr][0].z * NH + h]);
        vals[3] = s0v.w + bf2f(mpk[ch][rr][0][3]) + bf2f(vrow[(int)ibo[ch][rr][0].w * NH + h]);
        vals[4] = s1v.x + bf2f(mpk[ch][rr][1][0]) + bf2f(vrow[(int)ibo[ch][rr][1].x * NH + h]);
        vals[5] = s1v.y + bf2f(mpk[ch][rr][1][1]) + bf2f(vrow[(int)ibo[ch][rr][1].y * NH + h]);
        vals[6] = s1v.z + bf2f(mpk[ch][rr][1][2]) + bf2f(vrow[(int)ibo[ch][rr][1].z * NH + h]);
        vals[7] = s1v.w + bf2f(mpk[ch][rr][1][3]) + bf2f(vrow[(int)ibo[ch][rr][1].w * NH + h]);
        float mx = fmaxf(fmaxf(fmaxf(vals[0], vals[1]), fmaxf(vals[2], vals[3])),
                         fmaxf(fmaxf(vals[4], vals[5]), fmaxf(vals[6], vals[7])));
#pragma unroll
        for (int off = 32; off > 0; off >>= 1) mx = fmaxf(mx, __shfl_xor(mx, off));
        const float oldm = red_m[r];
        const float newm = fmaxf(oldm, mx);
        float sum = 0.f;
#pragma unroll
        for (int j = 0; j < 4; ++j) {
          const float p = __expf(vals[j] - newm);
          sum += p;
          plo[rr][j] = f2bf(p);
        }
#pragma unroll
        for (int j = 0; j < 4; ++j) {
          const float p = __expf(vals[4 + j] - newm);
          sum += p;
          phi[rr][j] = f2bf(p);
        }
#pragma unroll
        for (int off = 32; off > 0; off >>= 1) sum += __shfl_xor(sum, off);
        if (lane == 0) {
          const float rsc = (oldm <= -1e30f) ? 0.f : __expf(oldm - newm);
          red_r[r] = rsc;
          red_s[r] = red_s[r] * rsc + sum;
          red_m[r] = newm;
        }
      }
      // all S reads done for this wave's rows; overwrite with bf16 P in place
      asm volatile("" ::: "memory");
      __builtin_amdgcn_sched_barrier(0);
#pragma unroll
      for (int rr = 0; rr < 4; ++rr) {
        const int r = wid * 4 + rr;
        *reinterpret_cast<u16x4*>(Pb + (size_t)r * 1032 + lane * 4) = plo[rr];
        *reinterpret_cast<u16x4*>(Pb + (size_t)r * 1032 + 256 + lane * 4) = phi[rr];
      }
      __syncthreads();

      // ---- rescale + PV: wave owns d-tile d0
      {
        f32x4 rs;
#pragma unroll
        for (int r = 0; r < 4; ++r) rs[r] = red_r[l4 * 4 + r];
        oacc *= rs;
      }
#pragma unroll
      for (int ks = 0; ks < 16; ++ks) {
        const bf8 pa = *reinterpret_cast<const bf8*>(&Pb[(size_t)l15 * 1032 + ks * 32 + l4 * 8]);
        const bf8 vb = *reinterpret_cast<const bf8*>(
            &Vt[((size_t)bh * HD + d0 + l15) * TGT + srow0 + ks * 32 + l4 * 8]);
        __builtin_amdgcn_s_setprio(1);
        oacc = mfma_bf16(pa, vb, oacc);
        __builtin_amdgcn_s_setprio(0);
      }
      __syncthreads();
    }

    // ---- epilogue for this head
#pragma unroll
    for (int r = 0; r < 4; ++r) {
      const int row = l4 * 4 + r;
      const float inv = 1.f / red_s[row];
      const int tout = qrow0 + row;
      AT[((size_t)tout * BSZN + b) * EMB + h * HD + d0 + l15] = f2bf(oacc[r] * inv);
    }
    __syncthreads();
  }
}

// grid: 768 blocks. XCD-pair 2b,2b+1 owns batch b (default XCD = blockIdx%8).
__global__ __launch_bounds__(256, 3) void attn_kernel(
    const ushort_t* __restrict__ Q, const ushort_t* __restrict__ Kb,
    const ushort_t* __restrict__ Vt, const ushort_t* __restrict__ VMb,
    const unsigned char* __restrict__ ib8_main, const unsigned char* __restrict__ ib8_rel,
    const ushort_t* __restrict__ mmb, const ushort_t* __restrict__ mngb,
    ushort_t* __restrict__ AT) {
  __shared__ float S[16][516];
  __shared__ ushort_t VM_lds[16 * 512];
  __shared__ float red_m[16], red_s[16], red_r[16];

  const int n = blockIdx.x;
  const int xcd = n & 7;
  const int m = n >> 3;            // [0,96)
  const int b = xcd >> 1;
  const int qq = xcd & 1;
  const int idx = qq * 96 + m;     // [0,192) per b
  const int hg = idx & 1;
  const int zt = idx >> 1;         // [0,96)
  const int z = zt % 3;
  const int tile = zt / 3;

  if (z == 0) {
    const int qrow0 = tile * 16;
    attn_body<1>(b, tile, 0, hg, Q, Kb, Vt, VMb,
                 ib8_main + (size_t)b * TSEQ * TSEQ, TSEQ,
                 mmb, TSEQ, qrow0, AT, S, VM_lds, red_m, red_s, red_r);
  } else {
    const int g = z - 1;
    const int qrow0 = TSEQ + g * TSEQ + tile * 16;
    attn_body<2>(b, tile, g, hg, Q, Kb, Vt, VMb,
                 ib8_rel + (size_t)b * TSEQ * (2 * TSEQ), 2 * TSEQ,
                 mngb + (size_t)g * TSEQ * (2 * TSEQ), 2 * TSEQ,
                 qrow0, AT, S, VM_lds, red_m, red_s, red_r);
  }
}

extern "C" void kernel_launch(void* const* d_in, const int* in_sizes, int n_in,
                              void* d_out, int out_size, void* d_ws, size_t ws_size,
                              hipStream_t stream) {
  const float* query     = (const float*)d_in[0];
  const float* mask_main = (const float*)d_in[1];
  const float* mask_ng   = (const float*)d_in[2];
  const int*   ib_main   = (const int*)d_in[3];
  const int*   ib_rel    = (const int*)d_in[4];
  const float* w_in      = (const float*)d_in[5];
  const float* b_in      = (const float*)d_in[6];
  const float* w_out     = (const float*)d_in[7];
  const float* b_out     = (const float*)d_in[8];
  const float* w_rel     = (const float*)d_in[9];
  const float* b_rel     = (const float*)d_in[10];
  float* out = (float*)d_out;

  // workspace layout (u16 units); AT aliases qbf (dead after the VM gemm)
  ushort_t* qbf    = (ushort_t*)d_ws;           // 6291456
  ushort_t* winbf  = qbf + 6291456;             // 3145728
  ushort_t* woutbf = winbf + 3145728;           // 1048576
  ushort_t* relwbf = woutbf + 1048576;          // 524288
  ushort_t* Qb     = relwbf + 524288;           // 6291456
  ushort_t* Kbuf   = Qb + 6291456;              // 6291456
  ushort_t* Vtb    = Kbuf + 6291456;            // 6291456
  ushort_t* VMb    = Vtb + 6291456;             // 3145728
  ushort_t* mmb    = VMb + 3145728;             // 262144
  ushort_t* mngb   = mmb + 262144;              // 1048576
  unsigned char* ib8_main = (unsigned char*)(mngb + 1048576);   // 1048576 B
  unsigned char* ib8_rel  = ib8_main + 1048576;                 // 2097152 B
  ushort_t* AT     = qbf;                       // alias

  // fp32 -> bf16 (query, weights, masks)
  {
    const int total4 = 1572864 + 786432 + 262144 + 131072 + 65536 + 262144;
    cvt6_kernel<<<total4 / 256, 256, 0, stream>>>(query, w_in, w_out, w_rel,
                                                  mask_main, mask_ng,
                                                  qbf, winbf, woutbf, relwbf, mmb, mngb);
  }
  // bucket indices -> u8
  prep_ib_kernel<<<(262144 + 524288) / 256, 256, 0, stream>>>(ib_main, ib_rel,
                                                              ib8_main, ib8_rel);

  // in-projection -> Q/K/Vt
  gemm_bt<0><<<dim3(24, 48), 256, 0, stream>>>(qbf, winbf, b_in, nullptr,
                                               Qb, Kbuf, Vtb, MROWS, 3072, 1024);
  // relative-value table VM (bf16)
  gemm_bt<3><<<dim3(4, 48), 256, 0, stream>>>(qbf, relwbf, b_rel, nullptr,
                                              VMb, nullptr, nullptr, MROWS, 512, 1024);
  // fused attention: 8 heads per block, all blocks resident
  attn_kernel<<<768, 256, 0, stream>>>(Qb, Kbuf, Vtb, VMb, ib8_main, ib8_rel,
                                       mmb, mngb, AT);
  // out-projection
  gemm_bt<2><<<dim3(8, 48), 256, 0, stream>>>(AT, woutbf, b_out, out,
                                              nullptr, nullptr, nullptr, MROWS, 1024, 1024);
}